// Round 1
// baseline (1378.715 us; speedup 1.0000x reference)
//
#include <hip/hip_runtime.h>
#include <math.h>

#define N_NODES 32768
#define E_EDGES 262144
#define NFEAT   512
#define NHID    256
#define NCLASS  40
#define EPSV    0.1f
#define VLEN    1024
#define WLEN    32

// ---------------- init top_idx = 1 ----------------
__global__ void init_top(float* __restrict__ top) {
    top[blockIdx.x * 256 + threadIdx.x] = 1.0f;
}

// ---------------- zero agg ----------------
__global__ void zero_kernel(float4* __restrict__ p) {
    p[(size_t)blockIdx.x * 256 + threadIdx.x] = make_float4(0.f, 0.f, 0.f, 0.f);
}

// ---------------- h = relu(x @ Ws^T + b); h0 = h ----------------
// BM=BN=64, BK=32, 256 threads, 4x4 per thread.
__global__ __launch_bounds__(256) void gemm_relu(
        const float* __restrict__ x, const float* __restrict__ Ws,
        const float* __restrict__ b, float* __restrict__ h, float* __restrict__ h0) {
    __shared__ float As[32][64];
    __shared__ float Bs[32][64];
    int tid = threadIdx.x;
    int bx = blockIdx.x & 3;          // NHID/64 = 4 col tiles
    int by = blockIdx.x >> 2;         // 512 row tiles
    int tx = tid & 15, ty = tid >> 4;
    int row0 = by * 64, col0 = bx * 64;
    float acc[4][4] = {};
    for (int kt = 0; kt < NFEAT; kt += 32) {
#pragma unroll
        for (int i = 0; i < 2; ++i) {
            int li = tid * 2 + i;
            int m = li >> 3, c = (li & 7) * 4;
            float4 v = *(const float4*)&x[(size_t)(row0 + m) * NFEAT + kt + c];
            As[c + 0][m] = v.x; As[c + 1][m] = v.y; As[c + 2][m] = v.z; As[c + 3][m] = v.w;
            float4 w = *(const float4*)&Ws[(size_t)(col0 + m) * NFEAT + kt + c];
            Bs[c + 0][m] = w.x; Bs[c + 1][m] = w.y; Bs[c + 2][m] = w.z; Bs[c + 3][m] = w.w;
        }
        __syncthreads();
#pragma unroll
        for (int kk = 0; kk < 32; ++kk) {
            float4 a4 = *(const float4*)&As[kk][ty * 4];
            float4 b4 = *(const float4*)&Bs[kk][tx * 4];
            float a[4] = {a4.x, a4.y, a4.z, a4.w};
            float bb[4] = {b4.x, b4.y, b4.z, b4.w};
#pragma unroll
            for (int i = 0; i < 4; ++i)
#pragma unroll
                for (int j = 0; j < 4; ++j)
                    acc[i][j] += a[i] * bb[j];
        }
        __syncthreads();
    }
#pragma unroll
    for (int i = 0; i < 4; ++i) {
        int r = row0 + ty * 4 + i;
#pragma unroll
        for (int j = 0; j < 4; ++j) {
            int c = col0 + tx * 4 + j;
            float v = acc[i][j] + b[c];
            v = v > 0.f ? v : 0.f;
            h[(size_t)r * NHID + c]  = v;
            h0[(size_t)r * NHID + c] = v;
        }
    }
}

// ---------------- al[i] = h[i]·attl, ar[i] = h[i]·attr (one wave per node) ----------------
__global__ __launch_bounds__(256) void dots_kernel(
        const float* __restrict__ h, const float* __restrict__ attl,
        const float* __restrict__ attr_, float* __restrict__ al, float* __restrict__ ar) {
    int node = blockIdx.x * 4 + (threadIdx.x >> 6);
    int lane = threadIdx.x & 63;
    float4 hv = *(const float4*)&h[(size_t)node * NHID + lane * 4];
    float4 lv = *(const float4*)&attl[lane * 4];
    float4 rv = *(const float4*)&attr_[lane * 4];
    float sl = hv.x * lv.x + hv.y * lv.y + hv.z * lv.z + hv.w * lv.w;
    float sr = hv.x * rv.x + hv.y * rv.y + hv.z * rv.z + hv.w * rv.w;
#pragma unroll
    for (int off = 32; off; off >>= 1) {
        sl += __shfl_down(sl, off);
        sr += __shfl_down(sr, off);
    }
    if (lane == 0) { al[node] = sl; ar[node] = sr; }
}

// ---------------- per-edge: agg[dst] += tanh(al[s]+ar[d]) * w * h[src] ----------------
__global__ __launch_bounds__(256) void edge_kernel(
        const int* __restrict__ src, const int* __restrict__ dst,
        const float* __restrict__ eattr, const float* __restrict__ top,
        const float* __restrict__ al, const float* __restrict__ ar,
        const float* __restrict__ h, float* __restrict__ agg) {
    int e = blockIdx.x * 4 + (threadIdx.x >> 6);
    int lane = threadIdx.x & 63;
    int s = src[e], d = dst[e];
    float w = eattr[e] * top[s] * top[d];
    if (w == 0.f) return;                      // wave-uniform skip
    float coef = tanhf(al[s] + ar[d]) * w;
    float4 hv = *(const float4*)&h[(size_t)s * NHID + lane * 4];
    float* p = &agg[(size_t)d * NHID + lane * 4];
    atomicAdd(p + 0, coef * hv.x);
    atomicAdd(p + 1, coef * hv.y);
    atomicAdd(p + 2, coef * hv.z);
    atomicAdd(p + 3, coef * hv.w);
}

// ---------------- h = (agg + eps*h0) * top; nrm[i] = ||h[i]|| ----------------
__global__ __launch_bounds__(256) void combine_kernel(
        const float* __restrict__ agg, const float* __restrict__ h0,
        const float* __restrict__ top, float* __restrict__ h, float* __restrict__ nrm) {
    int node = blockIdx.x * 4 + (threadIdx.x >> 6);
    int lane = threadIdx.x & 63;
    float t = top[node];
    size_t base = (size_t)node * NHID + lane * 4;
    float4 a = *(const float4*)&agg[base];
    float4 z = *(const float4*)&h0[base];
    float4 v;
    v.x = (a.x + EPSV * z.x) * t;
    v.y = (a.y + EPSV * z.y) * t;
    v.z = (a.z + EPSV * z.z) * t;
    v.w = (a.w + EPSV * z.w) * t;
    *(float4*)&h[base] = v;
    float ss = v.x * v.x + v.y * v.y + v.z * v.z + v.w * v.w;
#pragma unroll
    for (int off = 32; off; off >>= 1) ss += __shfl_down(ss, off);
    if (lane == 0) nrm[node] = sqrtf(ss);
}

// ---------------- per-column stable top-k: drop rank >= drop_from ----------------
// rank = #{v' > v} + #{v' == v, r' < r}  (replicates stable argsort of -norm)
__global__ __launch_bounds__(1024) void topk_kernel(
        const float* __restrict__ nrm, float* __restrict__ top, int drop_from) {
    __shared__ float s[VLEN];
    int c = blockIdx.x;
    int r = threadIdx.x;
    float v = nrm[r * WLEN + c];
    s[r] = v;
    __syncthreads();
    int cnt = 0;
    for (int r2 = 0; r2 < VLEN; ++r2) {
        float v2 = s[r2];
        cnt += (v2 > v) || (v2 == v && r2 < r);
    }
    if (cnt >= drop_from) top[r * WLEN + c] = 0.f;
}

// ---------------- out[i] = (h[i] @ We^T + be) * top[i] ----------------
__global__ __launch_bounds__(64) void out_kernel(
        const float* __restrict__ h, const float* __restrict__ We,
        const float* __restrict__ be, const float* __restrict__ top,
        float* __restrict__ out) {
    __shared__ float sh[NHID];
    int node = blockIdx.x;
    int lane = threadIdx.x;
    *(float4*)&sh[lane * 4] = *(const float4*)&h[(size_t)node * NHID + lane * 4];
    __syncthreads();
    if (lane < NCLASS) {
        float accv = be[lane];
        for (int k = 0; k < NHID; ++k) accv += sh[k] * We[lane * NHID + k];
        out[(size_t)node * NCLASS + lane] = accv * top[node];
    }
}

extern "C" void kernel_launch(void* const* d_in, const int* in_sizes, int n_in,
                              void* d_out, int out_size, void* d_ws, size_t ws_size,
                              hipStream_t stream) {
    const float* x     = (const float*)d_in[0];
    const int*   ei    = (const int*)d_in[1];
    const float* eattr = (const float*)d_in[2];
    const float* Ws    = (const float*)d_in[3];
    const float* bs    = (const float*)d_in[4];   (void)bs;
    const float* attl  = (const float*)d_in[5];
    const float* attr_ = (const float*)d_in[6];
    const float* We    = (const float*)d_in[7];
    const float* be    = (const float*)d_in[8];
    float* out = (float*)d_out;

    char* ws = (char*)d_ws;
    const size_t HB = (size_t)N_NODES * NHID * sizeof(float);  // 32 MB
    float* h   = (float*)(ws);
    float* h0  = (float*)(ws + HB);
    float* agg = (float*)(ws + 2 * HB);
    float* al  = (float*)(ws + 3 * HB);
    float* ar  = (float*)(ws + 3 * HB + 131072);
    float* nrm = (float*)(ws + 3 * HB + 2 * 131072);
    float* top = (float*)(ws + 3 * HB + 3 * 131072);

    const int* srcp = ei;
    const int* dstp = ei + E_EDGES;

    init_top<<<N_NODES / 256, 256, 0, stream>>>(top);
    gemm_relu<<<(N_NODES / 64) * (NHID / 64), 256, 0, stream>>>(x, Ws, (const float*)d_in[4], h, h0);

    for (int l = 0; l < 2; ++l) {
        dots_kernel<<<N_NODES / 4, 256, 0, stream>>>(h, attl + l * NHID, attr_ + l * NHID, al, ar);
        zero_kernel<<<(N_NODES * NHID / 4) / 256, 256, 0, stream>>>((float4*)agg);
        edge_kernel<<<E_EDGES / 4, 256, 0, stream>>>(srcp, dstp, eattr, top, al, ar, h, agg);
        combine_kernel<<<N_NODES / 4, 256, 0, stream>>>(agg, h0, top, h, nrm);
        int drop_from = (l == 0) ? 256 : 128;   // ceil(1024*0.25/(l+1))
        topk_kernel<<<WLEN, VLEN, 0, stream>>>(nrm, top, drop_from);
    }

    out_kernel<<<N_NODES, 64, 0, stream>>>(h, We, be, top, out);
}

// Round 2
// 432.537 us; speedup vs baseline: 3.1875x; 3.1875x over previous
//
#include <hip/hip_runtime.h>
#include <math.h>

#define N_NODES 32768
#define E_EDGES 262144
#define NFEAT   512
#define NHID    256
#define NCLASS  40
#define EPSV    0.1f
#define VLEN    1024
#define WLEN    32

// ---------------- init: top=1, cnt=0, cur=0 ----------------
__global__ void init_kernel(float* __restrict__ top, int* __restrict__ cnt,
                            int* __restrict__ cur) {
    int i = blockIdx.x * 256 + threadIdx.x;
    top[i] = 1.0f;
    cnt[i] = 0;
    cur[i] = 0;
}

// ---------------- count in-degree ----------------
__global__ void count_kernel(const int* __restrict__ dst, int* __restrict__ cnt) {
    int e = blockIdx.x * 256 + threadIdx.x;
    atomicAdd(&cnt[dst[e]], 1);
}

// ---------------- exclusive prefix sum over 32768 counts (1 block) ----------------
__global__ __launch_bounds__(1024) void scan_kernel(const int* __restrict__ cnt,
                                                    int* __restrict__ off) {
    __shared__ int part[1024];
    int t = threadIdx.x;
    int base = t * 32;
    int local[32];
    int s = 0;
#pragma unroll
    for (int i = 0; i < 32; ++i) { local[i] = s; s += cnt[base + i]; }
    part[t] = s;
    __syncthreads();
    for (int d = 1; d < 1024; d <<= 1) {
        int v = (t >= d) ? part[t - d] : 0;
        __syncthreads();
        part[t] += v;
        __syncthreads();
    }
    int prev = (t == 0) ? 0 : part[t - 1];
#pragma unroll
    for (int i = 0; i < 32; ++i) off[base + i] = prev + local[i];
    if (t == 1023) off[N_NODES] = prev + s;
}

// ---------------- scatter edges into CSR slots ----------------
__global__ void scatter_kernel(const int* __restrict__ src, const int* __restrict__ dst,
                               const int* __restrict__ off, int* __restrict__ cur,
                               int* __restrict__ csr_src, int* __restrict__ csr_eid) {
    int e = blockIdx.x * 256 + threadIdx.x;
    int d = dst[e];
    int p = atomicAdd(&cur[d], 1);
    int k = off[d] + p;
    csr_src[k] = src[e];
    csr_eid[k] = e;
}

// ---------------- h = relu(x @ Ws^T + b); h0 = h ----------------
__global__ __launch_bounds__(256) void gemm_relu(
        const float* __restrict__ x, const float* __restrict__ Ws,
        const float* __restrict__ b, float* __restrict__ h, float* __restrict__ h0) {
    __shared__ float As[32][64];
    __shared__ float Bs[32][64];
    int tid = threadIdx.x;
    int bx = blockIdx.x & 3;
    int by = blockIdx.x >> 2;
    int tx = tid & 15, ty = tid >> 4;
    int row0 = by * 64, col0 = bx * 64;
    float acc[4][4] = {};
    for (int kt = 0; kt < NFEAT; kt += 32) {
#pragma unroll
        for (int i = 0; i < 2; ++i) {
            int li = tid * 2 + i;
            int m = li >> 3, c = (li & 7) * 4;
            float4 v = *(const float4*)&x[(size_t)(row0 + m) * NFEAT + kt + c];
            As[c + 0][m] = v.x; As[c + 1][m] = v.y; As[c + 2][m] = v.z; As[c + 3][m] = v.w;
            float4 w = *(const float4*)&Ws[(size_t)(col0 + m) * NFEAT + kt + c];
            Bs[c + 0][m] = w.x; Bs[c + 1][m] = w.y; Bs[c + 2][m] = w.z; Bs[c + 3][m] = w.w;
        }
        __syncthreads();
#pragma unroll
        for (int kk = 0; kk < 32; ++kk) {
            float4 a4 = *(const float4*)&As[kk][ty * 4];
            float4 b4 = *(const float4*)&Bs[kk][tx * 4];
            float a[4] = {a4.x, a4.y, a4.z, a4.w};
            float bb[4] = {b4.x, b4.y, b4.z, b4.w};
#pragma unroll
            for (int i = 0; i < 4; ++i)
#pragma unroll
                for (int j = 0; j < 4; ++j)
                    acc[i][j] += a[i] * bb[j];
        }
        __syncthreads();
    }
#pragma unroll
    for (int i = 0; i < 4; ++i) {
        int r = row0 + ty * 4 + i;
#pragma unroll
        for (int j = 0; j < 4; ++j) {
            int c = col0 + tx * 4 + j;
            float v = acc[i][j] + b[c];
            v = v > 0.f ? v : 0.f;
            h[(size_t)r * NHID + c]  = v;
            h0[(size_t)r * NHID + c] = v;
        }
    }
}

// ---------------- al[i] = h[i]·attl, ar[i] = h[i]·attr ----------------
__global__ __launch_bounds__(256) void dots_kernel(
        const float* __restrict__ h, const float* __restrict__ attl,
        const float* __restrict__ attr_, float* __restrict__ al, float* __restrict__ ar) {
    int node = blockIdx.x * 4 + (threadIdx.x >> 6);
    int lane = threadIdx.x & 63;
    float4 hv = *(const float4*)&h[(size_t)node * NHID + lane * 4];
    float4 lv = *(const float4*)&attl[lane * 4];
    float4 rv = *(const float4*)&attr_[lane * 4];
    float sl = hv.x * lv.x + hv.y * lv.y + hv.z * lv.z + hv.w * lv.w;
    float sr = hv.x * rv.x + hv.y * rv.y + hv.z * rv.z + hv.w * rv.w;
#pragma unroll
    for (int off = 32; off; off >>= 1) {
        sl += __shfl_down(sl, off);
        sr += __shfl_down(sr, off);
    }
    if (lane == 0) { al[node] = sl; ar[node] = sr; }
}

// ---------------- per-edge coefficient ----------------
__global__ void coef_kernel(const int* __restrict__ src, const int* __restrict__ dst,
                            const float* __restrict__ eattr, const float* __restrict__ top,
                            const float* __restrict__ al, const float* __restrict__ ar,
                            float* __restrict__ coef) {
    int e = blockIdx.x * 256 + threadIdx.x;
    int s = src[e], d = dst[e];
    float w = eattr[e] * top[s] * top[d];
    coef[e] = (w == 0.f) ? 0.f : tanhf(al[s] + ar[d]) * w;
}

// ---------------- gather: h_out[d] = (sum_e coef*h_in[src] + eps*h0[d]) * top[d]; nrm ----------------
__global__ __launch_bounds__(256) void gather_kernel(
        const int* __restrict__ csr_src, const int* __restrict__ csr_eid,
        const int* __restrict__ off, const float* __restrict__ coef,
        const float* __restrict__ h_in, const float* __restrict__ h0,
        const float* __restrict__ top, float* __restrict__ h_out,
        float* __restrict__ nrm) {
    int node = blockIdx.x * 4 + (threadIdx.x >> 6);
    int lane = threadIdx.x & 63;
    size_t base = (size_t)node * NHID + lane * 4;
    float t = top[node];
    if (t == 0.f) {
        *(float4*)&h_out[base] = make_float4(0.f, 0.f, 0.f, 0.f);
        if (lane == 0) nrm[node] = 0.f;
        return;
    }
    int k0 = off[node], k1 = off[node + 1];
    float4 acc = make_float4(0.f, 0.f, 0.f, 0.f);
    for (int k = k0; k < k1; ++k) {
        float c = coef[csr_eid[k]];
        if (c != 0.f) {
            int s = csr_src[k];
            float4 hv = *(const float4*)&h_in[(size_t)s * NHID + lane * 4];
            acc.x += c * hv.x; acc.y += c * hv.y;
            acc.z += c * hv.z; acc.w += c * hv.w;
        }
    }
    float4 z = *(const float4*)&h0[base];
    float4 v;
    v.x = acc.x + EPSV * z.x;
    v.y = acc.y + EPSV * z.y;
    v.z = acc.z + EPSV * z.z;
    v.w = acc.w + EPSV * z.w;
    *(float4*)&h_out[base] = v;
    float ss = v.x * v.x + v.y * v.y + v.z * v.z + v.w * v.w;
#pragma unroll
    for (int o = 32; o; o >>= 1) ss += __shfl_down(ss, o);
    if (lane == 0) nrm[node] = sqrtf(ss);
}

// ---------------- per-column stable top-k ----------------
__global__ __launch_bounds__(1024) void topk_kernel(
        const float* __restrict__ nrm, float* __restrict__ top, int drop_from) {
    __shared__ float s[VLEN];
    int c = blockIdx.x;
    int r = threadIdx.x;
    float v = nrm[r * WLEN + c];
    s[r] = v;
    __syncthreads();
    int cnt = 0;
    for (int r2 = 0; r2 < VLEN; ++r2) {
        float v2 = s[r2];
        cnt += (v2 > v) || (v2 == v && r2 < r);
    }
    if (cnt >= drop_from) top[r * WLEN + c] = 0.f;
}

// ---------------- out[i] = (h[i] @ We^T + be) * top[i]; We staged in LDS ----------------
__global__ __launch_bounds__(256) void out_kernel(
        const float* __restrict__ h, const float* __restrict__ We,
        const float* __restrict__ be, const float* __restrict__ top,
        float* __restrict__ out) {
    __shared__ float sWe[NCLASS * 257];   // +1-pad: lane*257 stride -> <=2-way (free)
    __shared__ float sh[4][NHID];
    int tid = threadIdx.x;
    for (int i = tid; i < NCLASS * NHID; i += 256)
        sWe[(i >> 8) * 257 + (i & 255)] = We[i];
    int node = blockIdx.x * 4 + (tid >> 6);
    int lane = tid & 63;
    int w = tid >> 6;
    *(float4*)&sh[w][lane * 4] = *(const float4*)&h[(size_t)node * NHID + lane * 4];
    __syncthreads();
    if (lane < NCLASS) {
        float accv = be[lane];
        const float* wr = &sWe[lane * 257];
#pragma unroll 8
        for (int k = 0; k < NHID; ++k) accv += sh[w][k] * wr[k];
        out[(size_t)node * NCLASS + lane] = accv * top[node];
    }
}

extern "C" void kernel_launch(void* const* d_in, const int* in_sizes, int n_in,
                              void* d_out, int out_size, void* d_ws, size_t ws_size,
                              hipStream_t stream) {
    const float* x     = (const float*)d_in[0];
    const int*   ei    = (const int*)d_in[1];
    const float* eattr = (const float*)d_in[2];
    const float* Ws    = (const float*)d_in[3];
    const float* bs    = (const float*)d_in[4];
    const float* attl  = (const float*)d_in[5];
    const float* attr_ = (const float*)d_in[6];
    const float* We    = (const float*)d_in[7];
    const float* be    = (const float*)d_in[8];
    float* out = (float*)d_out;

    char* ws = (char*)d_ws;
    const size_t HB = (size_t)N_NODES * NHID * sizeof(float);   // 32 MB
    float* hA  = (float*)(ws);
    float* hB  = (float*)(ws + HB);
    float* h0  = (float*)(ws + 2 * HB);
    char* sm = ws + 3 * HB;
    float* al      = (float*)(sm);               sm += 131072;
    float* ar      = (float*)(sm);               sm += 131072;
    float* nrm     = (float*)(sm);               sm += 131072;
    float* top     = (float*)(sm);               sm += 131072;
    int*   cnt     = (int*)(sm);                 sm += 131072;
    int*   cur     = (int*)(sm);                 sm += 131072;
    int*   off     = (int*)(sm);                 sm += 262144;  // 32769 ints
    int*   csr_src = (int*)(sm);                 sm += E_EDGES * 4;
    int*   csr_eid = (int*)(sm);                 sm += E_EDGES * 4;
    float* coef    = (float*)(sm);               sm += E_EDGES * 4;

    const int* srcp = ei;
    const int* dstp = ei + E_EDGES;

    init_kernel<<<N_NODES / 256, 256, 0, stream>>>(top, cnt, cur);
    count_kernel<<<E_EDGES / 256, 256, 0, stream>>>(dstp, cnt);
    scan_kernel<<<1, 1024, 0, stream>>>(cnt, off);
    scatter_kernel<<<E_EDGES / 256, 256, 0, stream>>>(srcp, dstp, off, cur, csr_src, csr_eid);

    gemm_relu<<<(N_NODES / 64) * (NHID / 64), 256, 0, stream>>>(x, Ws, bs, hA, h0);

    float* hin = hA;
    float* hout = hB;
    for (int l = 0; l < 2; ++l) {
        dots_kernel<<<N_NODES / 4, 256, 0, stream>>>(hin, attl + l * NHID, attr_ + l * NHID, al, ar);
        coef_kernel<<<E_EDGES / 256, 256, 0, stream>>>(srcp, dstp, eattr, top, al, ar, coef);
        gather_kernel<<<N_NODES / 4, 256, 0, stream>>>(csr_src, csr_eid, off, coef,
                                                       hin, h0, top, hout, nrm);
        int drop_from = (l == 0) ? 256 : 128;
        topk_kernel<<<WLEN, VLEN, 0, stream>>>(nrm, top, drop_from);
        float* tmp = hin; hin = hout; hout = tmp;
    }

    out_kernel<<<N_NODES / 4, 256, 0, stream>>>(hin, We, be, top, out);
}

// Round 3
// 347.570 us; speedup vs baseline: 3.9667x; 1.2445x over previous
//
#include <hip/hip_runtime.h>
#include <math.h>

#define N_NODES 32768
#define E_EDGES 262144
#define NFEAT   512
#define NHID    256
#define NCLASS  40
#define EPSV    0.1f
#define VLEN    1024
#define WLEN    32

typedef __attribute__((ext_vector_type(8))) short bf16x8;
typedef __attribute__((ext_vector_type(4))) float f32x4;
typedef __attribute__((ext_vector_type(8))) unsigned short us8;

__device__ inline unsigned short f2bf(float f) {
    unsigned int u = __builtin_bit_cast(unsigned int, f);
    return (unsigned short)((u + 0x7FFFu + ((u >> 16) & 1u)) >> 16);
}
__device__ inline float bf2f(unsigned short h) {
    unsigned int u = ((unsigned int)h) << 16;
    return __builtin_bit_cast(float, u);
}

// ---------------- init: top=1, cnt=0, cur=0 ----------------
__global__ void init_kernel(float* __restrict__ top, int* __restrict__ cnt,
                            int* __restrict__ cur) {
    int i = blockIdx.x * 256 + threadIdx.x;
    top[i] = 1.0f;
    cnt[i] = 0;
    cur[i] = 0;
}

// ---------------- count in-degree ----------------
__global__ void count_kernel(const int* __restrict__ dst, int* __restrict__ cnt) {
    int e = blockIdx.x * 256 + threadIdx.x;
    atomicAdd(&cnt[dst[e]], 1);
}

// ---------------- exclusive prefix sum over 32768 counts (1 block) ----------------
__global__ __launch_bounds__(1024) void scan_kernel(const int* __restrict__ cnt,
                                                    int* __restrict__ off) {
    __shared__ int part[1024];
    int t = threadIdx.x;
    int base = t * 32;
    int local[32];
    int s = 0;
#pragma unroll
    for (int i = 0; i < 32; ++i) { local[i] = s; s += cnt[base + i]; }
    part[t] = s;
    __syncthreads();
    for (int d = 1; d < 1024; d <<= 1) {
        int v = (t >= d) ? part[t - d] : 0;
        __syncthreads();
        part[t] += v;
        __syncthreads();
    }
    int prev = (t == 0) ? 0 : part[t - 1];
#pragma unroll
    for (int i = 0; i < 32; ++i) off[base + i] = prev + local[i];
    if (t == 1023) off[N_NODES] = prev + s;
}

// ---------------- scatter edges into CSR slots ----------------
__global__ void scatter_kernel(const int* __restrict__ src, const int* __restrict__ dst,
                               const int* __restrict__ off, int* __restrict__ cur,
                               int* __restrict__ csr_src, int* __restrict__ csr_eid) {
    int e = blockIdx.x * 256 + threadIdx.x;
    int d = dst[e];
    int p = atomicAdd(&cur[d], 1);
    int k = off[d] + p;
    csr_src[k] = src[e];
    csr_eid[k] = e;
}

// ---------------- split Ws into bf16 hi/lo (once) ----------------
__global__ void wsplit_kernel(const float* __restrict__ Ws,
                              unsigned short* __restrict__ Whi,
                              unsigned short* __restrict__ Wlo) {
    int i = blockIdx.x * 256 + threadIdx.x;   // float4 index
    float4 v = ((const float4*)Ws)[i];
    ushort4 hh, ll;
    hh.x = f2bf(v.x); ll.x = f2bf(v.x - bf2f(hh.x));
    hh.y = f2bf(v.y); ll.y = f2bf(v.y - bf2f(hh.y));
    hh.z = f2bf(v.z); ll.z = f2bf(v.z - bf2f(hh.z));
    hh.w = f2bf(v.w); ll.w = f2bf(v.w - bf2f(hh.w));
    ((ushort4*)Whi)[i] = hh;
    ((ushort4*)Wlo)[i] = ll;
}

// ---------------- h0 = relu(x @ Ws^T + b) via split-bf16 MFMA ----------------
// BM=64 rows/block, BN=256 (full hid), BK=32. 4 waves; wave w owns cols w*64..w*64+63.
// LDS rows padded to 40 bf16 (80 B stride, 16B-aligned) -> b128 reads spread all 32 banks.
#define ASTR 40
#define BSTR 40
__global__ __launch_bounds__(256) void gemm_mfma(
        const float* __restrict__ x, const unsigned short* __restrict__ Whi,
        const unsigned short* __restrict__ Wlo, const float* __restrict__ b,
        float* __restrict__ h0) {
    __shared__ unsigned short Ah[64 * ASTR];
    __shared__ unsigned short Al[64 * ASTR];
    __shared__ unsigned short Bh[256 * BSTR];
    __shared__ unsigned short Bl[256 * BSTR];
    int tid  = threadIdx.x;
    int w    = tid >> 6;
    int lane = tid & 63;
    int m16  = lane & 15;
    int kblk = lane >> 4;          // 0..3, fragment k-offset = kblk*8
    int row0 = blockIdx.x * 64;

    f32x4 acc[4][4];
#pragma unroll
    for (int mr = 0; mr < 4; ++mr)
#pragma unroll
        for (int nr = 0; nr < 4; ++nr)
#pragma unroll
            for (int e = 0; e < 4; ++e) acc[mr][nr][e] = 0.f;

    for (int kt = 0; kt < NFEAT; kt += 32) {
        // stage A: 64x32 fp32 -> bf16 hi/lo (512 float4, 2/thread)
#pragma unroll
        for (int i = 0; i < 2; ++i) {
            int f = tid + 256 * i;
            int row = f >> 3, k4 = f & 7;
            float4 v = *(const float4*)&x[(size_t)(row0 + row) * NFEAT + kt + k4 * 4];
            ushort4 hh, ll;
            hh.x = f2bf(v.x); ll.x = f2bf(v.x - bf2f(hh.x));
            hh.y = f2bf(v.y); ll.y = f2bf(v.y - bf2f(hh.y));
            hh.z = f2bf(v.z); ll.z = f2bf(v.z - bf2f(hh.z));
            hh.w = f2bf(v.w); ll.w = f2bf(v.w - bf2f(hh.w));
            *(ushort4*)&Ah[row * ASTR + k4 * 4] = hh;
            *(ushort4*)&Al[row * ASTR + k4 * 4] = ll;
        }
        // stage B: 256x32 bf16 hi/lo (1024 16B-chunks, 4/thread each)
#pragma unroll
        for (int i = 0; i < 4; ++i) {
            int c = tid + 256 * i;
            int row = c >> 2, k8 = c & 3;
            us8 vh = *(const us8*)&Whi[row * NFEAT + kt + k8 * 8];
            us8 vl = *(const us8*)&Wlo[row * NFEAT + kt + k8 * 8];
            *(us8*)&Bh[row * BSTR + k8 * 8] = vh;
            *(us8*)&Bl[row * BSTR + k8 * 8] = vl;
        }
        __syncthreads();

        bf16x8 bh[4], bl[4];
#pragma unroll
        for (int nr = 0; nr < 4; ++nr) {
            int r = w * 64 + nr * 16 + m16;
            bh[nr] = *(const bf16x8*)&Bh[r * BSTR + kblk * 8];
            bl[nr] = *(const bf16x8*)&Bl[r * BSTR + kblk * 8];
        }
#pragma unroll
        for (int mr = 0; mr < 4; ++mr) {
            int r = mr * 16 + m16;
            bf16x8 ah  = *(const bf16x8*)&Ah[r * ASTR + kblk * 8];
            bf16x8 alo = *(const bf16x8*)&Al[r * ASTR + kblk * 8];
#pragma unroll
            for (int nr = 0; nr < 4; ++nr) {
                acc[mr][nr] = __builtin_amdgcn_mfma_f32_16x16x32_bf16(ah,  bh[nr], acc[mr][nr], 0, 0, 0);
                acc[mr][nr] = __builtin_amdgcn_mfma_f32_16x16x32_bf16(ah,  bl[nr], acc[mr][nr], 0, 0, 0);
                acc[mr][nr] = __builtin_amdgcn_mfma_f32_16x16x32_bf16(alo, bh[nr], acc[mr][nr], 0, 0, 0);
            }
        }
        __syncthreads();
    }
    // epilogue: D row=(lane>>4)*4+r, col=lane&15 (m89-verified)
#pragma unroll
    for (int nr = 0; nr < 4; ++nr) {
        int col = w * 64 + nr * 16 + m16;
        float bias = b[col];
#pragma unroll
        for (int mr = 0; mr < 4; ++mr) {
#pragma unroll
            for (int r = 0; r < 4; ++r) {
                int row = row0 + mr * 16 + kblk * 4 + r;
                float v = acc[mr][nr][r] + bias;
                h0[(size_t)row * NHID + col] = v > 0.f ? v : 0.f;
            }
        }
    }
}

// ---------------- al[i] = h[i]·attl, ar[i] = h[i]·attr ----------------
__global__ __launch_bounds__(256) void dots_kernel(
        const float* __restrict__ h, const float* __restrict__ attl,
        const float* __restrict__ attr_, float* __restrict__ al, float* __restrict__ ar) {
    int node = blockIdx.x * 4 + (threadIdx.x >> 6);
    int lane = threadIdx.x & 63;
    float4 hv = *(const float4*)&h[(size_t)node * NHID + lane * 4];
    float4 lv = *(const float4*)&attl[lane * 4];
    float4 rv = *(const float4*)&attr_[lane * 4];
    float sl = hv.x * lv.x + hv.y * lv.y + hv.z * lv.z + hv.w * lv.w;
    float sr = hv.x * rv.x + hv.y * rv.y + hv.z * rv.z + hv.w * rv.w;
#pragma unroll
    for (int off = 32; off; off >>= 1) {
        sl += __shfl_down(sl, off);
        sr += __shfl_down(sr, off);
    }
    if (lane == 0) { al[node] = sl; ar[node] = sr; }
}

// ---------------- per-edge coefficient ----------------
__global__ void coef_kernel(const int* __restrict__ src, const int* __restrict__ dst,
                            const float* __restrict__ eattr, const float* __restrict__ top,
                            const float* __restrict__ al, const float* __restrict__ ar,
                            float* __restrict__ coef) {
    int e = blockIdx.x * 256 + threadIdx.x;
    int s = src[e], d = dst[e];
    float w = eattr[e] * top[s] * top[d];
    coef[e] = (w == 0.f) ? 0.f : tanhf(al[s] + ar[d]) * w;
}

// ---------------- gather: h_out[d] = (sum_e coef*h_in[src] + eps*h0[d]) * top[d]; nrm ----------------
__global__ __launch_bounds__(256) void gather_kernel(
        const int* __restrict__ csr_src, const int* __restrict__ csr_eid,
        const int* __restrict__ off, const float* __restrict__ coef,
        const float* __restrict__ h_in, const float* __restrict__ h0,
        const float* __restrict__ top, float* __restrict__ h_out,
        float* __restrict__ nrm) {
    int node = blockIdx.x * 4 + (threadIdx.x >> 6);
    int lane = threadIdx.x & 63;
    size_t base = (size_t)node * NHID + lane * 4;
    float t = top[node];
    if (t == 0.f) {
        *(float4*)&h_out[base] = make_float4(0.f, 0.f, 0.f, 0.f);
        if (lane == 0) nrm[node] = 0.f;
        return;
    }
    int k0 = off[node], k1 = off[node + 1];
    float4 acc = make_float4(0.f, 0.f, 0.f, 0.f);
    for (int k = k0; k < k1; ++k) {
        float c = coef[csr_eid[k]];
        if (c != 0.f) {
            int s = csr_src[k];
            float4 hv = *(const float4*)&h_in[(size_t)s * NHID + lane * 4];
            acc.x += c * hv.x; acc.y += c * hv.y;
            acc.z += c * hv.z; acc.w += c * hv.w;
        }
    }
    float4 z = *(const float4*)&h0[base];
    float4 v;
    v.x = acc.x + EPSV * z.x;
    v.y = acc.y + EPSV * z.y;
    v.z = acc.z + EPSV * z.z;
    v.w = acc.w + EPSV * z.w;
    *(float4*)&h_out[base] = v;
    float ss = v.x * v.x + v.y * v.y + v.z * v.z + v.w * v.w;
#pragma unroll
    for (int o = 32; o; o >>= 1) ss += __shfl_down(ss, o);
    if (lane == 0) nrm[node] = sqrtf(ss);
}

// ---------------- per-column stable top-k ----------------
__global__ __launch_bounds__(1024) void topk_kernel(
        const float* __restrict__ nrm, float* __restrict__ top, int drop_from) {
    __shared__ float s[VLEN];
    int c = blockIdx.x;
    int r = threadIdx.x;
    float v = nrm[r * WLEN + c];
    s[r] = v;
    __syncthreads();
    int cnt = 0;
    for (int r2 = 0; r2 < VLEN; ++r2) {
        float v2 = s[r2];
        cnt += (v2 > v) || (v2 == v && r2 < r);
    }
    if (cnt >= drop_from) top[r * WLEN + c] = 0.f;
}

// ---------------- out[i] = (h[i] @ We^T + be) * top[i]; We staged in LDS ----------------
__global__ __launch_bounds__(256) void out_kernel(
        const float* __restrict__ h, const float* __restrict__ We,
        const float* __restrict__ be, const float* __restrict__ top,
        float* __restrict__ out) {
    __shared__ float sWe[NCLASS * 257];
    __shared__ float sh[4][NHID];
    int tid = threadIdx.x;
    for (int i = tid; i < NCLASS * NHID; i += 256)
        sWe[(i >> 8) * 257 + (i & 255)] = We[i];
    int node = blockIdx.x * 4 + (tid >> 6);
    int lane = tid & 63;
    int w = tid >> 6;
    *(float4*)&sh[w][lane * 4] = *(const float4*)&h[(size_t)node * NHID + lane * 4];
    __syncthreads();
    if (lane < NCLASS) {
        float accv = be[lane];
        const float* wr = &sWe[lane * 257];
#pragma unroll 8
        for (int k = 0; k < NHID; ++k) accv += sh[w][k] * wr[k];
        out[(size_t)node * NCLASS + lane] = accv * top[node];
    }
}

extern "C" void kernel_launch(void* const* d_in, const int* in_sizes, int n_in,
                              void* d_out, int out_size, void* d_ws, size_t ws_size,
                              hipStream_t stream) {
    const float* x     = (const float*)d_in[0];
    const int*   ei    = (const int*)d_in[1];
    const float* eattr = (const float*)d_in[2];
    const float* Ws    = (const float*)d_in[3];
    const float* bs    = (const float*)d_in[4];
    const float* attl  = (const float*)d_in[5];
    const float* attr_ = (const float*)d_in[6];
    const float* We    = (const float*)d_in[7];
    const float* be    = (const float*)d_in[8];
    float* out = (float*)d_out;

    char* ws = (char*)d_ws;
    const size_t HB = (size_t)N_NODES * NHID * sizeof(float);   // 32 MB
    float* hA  = (float*)(ws);
    float* hB  = (float*)(ws + HB);
    float* h0  = (float*)(ws + 2 * HB);
    char* sm = ws + 3 * HB;
    float* al      = (float*)(sm);               sm += 131072;
    float* ar      = (float*)(sm);               sm += 131072;
    float* nrm     = (float*)(sm);               sm += 131072;
    float* top     = (float*)(sm);               sm += 131072;
    int*   cnt     = (int*)(sm);                 sm += 131072;
    int*   cur     = (int*)(sm);                 sm += 131072;
    int*   off     = (int*)(sm);                 sm += 262144;  // 32769 ints
    int*   csr_src = (int*)(sm);                 sm += E_EDGES * 4;
    int*   csr_eid = (int*)(sm);                 sm += E_EDGES * 4;
    float* coef    = (float*)(sm);               sm += E_EDGES * 4;
    unsigned short* Whi = (unsigned short*)(sm); sm += NHID * NFEAT * 2;
    unsigned short* Wlo = (unsigned short*)(sm); sm += NHID * NFEAT * 2;

    const int* srcp = ei;
    const int* dstp = ei + E_EDGES;

    init_kernel<<<N_NODES / 256, 256, 0, stream>>>(top, cnt, cur);
    count_kernel<<<E_EDGES / 256, 256, 0, stream>>>(dstp, cnt);
    scan_kernel<<<1, 1024, 0, stream>>>(cnt, off);
    scatter_kernel<<<E_EDGES / 256, 256, 0, stream>>>(srcp, dstp, off, cur, csr_src, csr_eid);

    wsplit_kernel<<<(NHID * NFEAT / 4) / 256, 256, 0, stream>>>(Ws, Whi, Wlo);
    gemm_mfma<<<N_NODES / 64, 256, 0, stream>>>(x, Whi, Wlo, bs, h0);

    float* hin = h0;
    float* hout = hA;
    for (int l = 0; l < 2; ++l) {
        dots_kernel<<<N_NODES / 4, 256, 0, stream>>>(hin, attl + l * NHID, attr_ + l * NHID, al, ar);
        coef_kernel<<<E_EDGES / 256, 256, 0, stream>>>(srcp, dstp, eattr, top, al, ar, coef);
        gather_kernel<<<N_NODES / 4, 256, 0, stream>>>(csr_src, csr_eid, off, coef,
                                                       hin, h0, top, hout, nrm);
        int drop_from = (l == 0) ? 256 : 128;
        topk_kernel<<<WLEN, VLEN, 0, stream>>>(nrm, top, drop_from);
        hin = hout;
        hout = (hout == hA) ? hB : hA;
    }

    out_kernel<<<N_NODES / 4, 256, 0, stream>>>(hin, We, be, top, out);
}

// Round 4
// 265.389 us; speedup vs baseline: 5.1951x; 1.3097x over previous
//
#include <hip/hip_runtime.h>
#include <math.h>

#define N_NODES 32768
#define E_EDGES 262144
#define NFEAT   512
#define NHID    256
#define NCLASS  40
#define EPSV    0.1f
#define VLEN    1024
#define WLEN    32

typedef __attribute__((ext_vector_type(8))) short bf16x8;
typedef __attribute__((ext_vector_type(4))) float f32x4;
typedef __attribute__((ext_vector_type(8))) unsigned short us8;

__device__ inline unsigned short f2bf(float f) {
    unsigned int u = __builtin_bit_cast(unsigned int, f);
    return (unsigned short)((u + 0x7FFFu + ((u >> 16) & 1u)) >> 16);
}
__device__ inline float bf2f(unsigned short h) {
    unsigned int u = ((unsigned int)h) << 16;
    return __builtin_bit_cast(float, u);
}

// ---------------- init: top=1, cnt=0, cur=0 ----------------
__global__ void init_kernel(float* __restrict__ top, int* __restrict__ cnt,
                            int* __restrict__ cur) {
    int i = blockIdx.x * 256 + threadIdx.x;
    top[i] = 1.0f;
    cnt[i] = 0;
    cur[i] = 0;
}

// ---------------- count in-degree ----------------
__global__ void count_kernel(const int* __restrict__ dst, int* __restrict__ cnt) {
    int e = blockIdx.x * 256 + threadIdx.x;
    atomicAdd(&cnt[dst[e]], 1);
}

// ---------------- exclusive prefix sum over 32768 counts (1 block) ----------------
__global__ __launch_bounds__(1024) void scan_kernel(const int* __restrict__ cnt,
                                                    int* __restrict__ off) {
    __shared__ int part[1024];
    int t = threadIdx.x;
    int base = t * 32;
    int local[32];
    int s = 0;
#pragma unroll
    for (int i = 0; i < 32; ++i) { local[i] = s; s += cnt[base + i]; }
    part[t] = s;
    __syncthreads();
    for (int d = 1; d < 1024; d <<= 1) {
        int v = (t >= d) ? part[t - d] : 0;
        __syncthreads();
        part[t] += v;
        __syncthreads();
    }
    int prev = (t == 0) ? 0 : part[t - 1];
#pragma unroll
    for (int i = 0; i < 32; ++i) off[base + i] = prev + local[i];
    if (t == 1023) off[N_NODES] = prev + s;
}

// ---------------- scatter edges into CSR slots (store src, dst, eid) ----------------
__global__ void scatter_kernel(const int* __restrict__ src, const int* __restrict__ dst,
                               const int* __restrict__ off, int* __restrict__ cur,
                               int* __restrict__ csr_src, int* __restrict__ csr_dst,
                               int* __restrict__ csr_eid) {
    int e = blockIdx.x * 256 + threadIdx.x;
    int d = dst[e];
    int p = atomicAdd(&cur[d], 1);
    int k = off[d] + p;
    csr_src[k] = src[e];
    csr_dst[k] = d;
    csr_eid[k] = e;
}

// ---------------- split Ws into bf16 hi/lo (once) ----------------
__global__ void wsplit_kernel(const float* __restrict__ Ws,
                              unsigned short* __restrict__ Whi,
                              unsigned short* __restrict__ Wlo) {
    int i = blockIdx.x * 256 + threadIdx.x;   // float4 index
    float4 v = ((const float4*)Ws)[i];
    ushort4 hh, ll;
    hh.x = f2bf(v.x); ll.x = f2bf(v.x - bf2f(hh.x));
    hh.y = f2bf(v.y); ll.y = f2bf(v.y - bf2f(hh.y));
    hh.z = f2bf(v.z); ll.z = f2bf(v.z - bf2f(hh.z));
    hh.w = f2bf(v.w); ll.w = f2bf(v.w - bf2f(hh.w));
    ((ushort4*)Whi)[i] = hh;
    ((ushort4*)Wlo)[i] = ll;
}

// ---------------- h0 = relu(x @ Ws^T + b) via split-bf16 MFMA ----------------
#define ASTR 40
#define BSTR 40
__global__ __launch_bounds__(256) void gemm_mfma(
        const float* __restrict__ x, const unsigned short* __restrict__ Whi,
        const unsigned short* __restrict__ Wlo, const float* __restrict__ b,
        float* __restrict__ h0) {
    __shared__ unsigned short Ah[64 * ASTR];
    __shared__ unsigned short Al[64 * ASTR];
    __shared__ unsigned short Bh[256 * BSTR];
    __shared__ unsigned short Bl[256 * BSTR];
    int tid  = threadIdx.x;
    int w    = tid >> 6;
    int lane = tid & 63;
    int m16  = lane & 15;
    int kblk = lane >> 4;
    int row0 = blockIdx.x * 64;

    f32x4 acc[4][4];
#pragma unroll
    for (int mr = 0; mr < 4; ++mr)
#pragma unroll
        for (int nr = 0; nr < 4; ++nr)
#pragma unroll
            for (int e = 0; e < 4; ++e) acc[mr][nr][e] = 0.f;

    for (int kt = 0; kt < NFEAT; kt += 32) {
#pragma unroll
        for (int i = 0; i < 2; ++i) {
            int f = tid + 256 * i;
            int row = f >> 3, k4 = f & 7;
            float4 v = *(const float4*)&x[(size_t)(row0 + row) * NFEAT + kt + k4 * 4];
            ushort4 hh, ll;
            hh.x = f2bf(v.x); ll.x = f2bf(v.x - bf2f(hh.x));
            hh.y = f2bf(v.y); ll.y = f2bf(v.y - bf2f(hh.y));
            hh.z = f2bf(v.z); ll.z = f2bf(v.z - bf2f(hh.z));
            hh.w = f2bf(v.w); ll.w = f2bf(v.w - bf2f(hh.w));
            *(ushort4*)&Ah[row * ASTR + k4 * 4] = hh;
            *(ushort4*)&Al[row * ASTR + k4 * 4] = ll;
        }
#pragma unroll
        for (int i = 0; i < 4; ++i) {
            int c = tid + 256 * i;
            int row = c >> 2, k8 = c & 3;
            us8 vh = *(const us8*)&Whi[row * NFEAT + kt + k8 * 8];
            us8 vl = *(const us8*)&Wlo[row * NFEAT + kt + k8 * 8];
            *(us8*)&Bh[row * BSTR + k8 * 8] = vh;
            *(us8*)&Bl[row * BSTR + k8 * 8] = vl;
        }
        __syncthreads();

        bf16x8 bh[4], bl[4];
#pragma unroll
        for (int nr = 0; nr < 4; ++nr) {
            int r = w * 64 + nr * 16 + m16;
            bh[nr] = *(const bf16x8*)&Bh[r * BSTR + kblk * 8];
            bl[nr] = *(const bf16x8*)&Bl[r * BSTR + kblk * 8];
        }
#pragma unroll
        for (int mr = 0; mr < 4; ++mr) {
            int r = mr * 16 + m16;
            bf16x8 ah  = *(const bf16x8*)&Ah[r * ASTR + kblk * 8];
            bf16x8 alo = *(const bf16x8*)&Al[r * ASTR + kblk * 8];
#pragma unroll
            for (int nr = 0; nr < 4; ++nr) {
                acc[mr][nr] = __builtin_amdgcn_mfma_f32_16x16x32_bf16(ah,  bh[nr], acc[mr][nr], 0, 0, 0);
                acc[mr][nr] = __builtin_amdgcn_mfma_f32_16x16x32_bf16(ah,  bl[nr], acc[mr][nr], 0, 0, 0);
                acc[mr][nr] = __builtin_amdgcn_mfma_f32_16x16x32_bf16(alo, bh[nr], acc[mr][nr], 0, 0, 0);
            }
        }
        __syncthreads();
    }
#pragma unroll
    for (int nr = 0; nr < 4; ++nr) {
        int col = w * 64 + nr * 16 + m16;
        float bias = b[col];
#pragma unroll
        for (int mr = 0; mr < 4; ++mr) {
#pragma unroll
            for (int r = 0; r < 4; ++r) {
                int row = row0 + mr * 16 + kblk * 4 + r;
                float v = acc[mr][nr][r] + bias;
                h0[(size_t)row * NHID + col] = v > 0.f ? v : 0.f;
            }
        }
    }
}

// ---------------- al[i] = h[i]·attl, ar[i] = h[i]·attr ----------------
__global__ __launch_bounds__(256) void dots_kernel(
        const float* __restrict__ h, const float* __restrict__ attl,
        const float* __restrict__ attr_, float* __restrict__ al, float* __restrict__ ar) {
    int node = blockIdx.x * 4 + (threadIdx.x >> 6);
    int lane = threadIdx.x & 63;
    float4 hv = *(const float4*)&h[(size_t)node * NHID + lane * 4];
    float4 lv = *(const float4*)&attl[lane * 4];
    float4 rv = *(const float4*)&attr_[lane * 4];
    float sl = hv.x * lv.x + hv.y * lv.y + hv.z * lv.z + hv.w * lv.w;
    float sr = hv.x * rv.x + hv.y * rv.y + hv.z * rv.z + hv.w * rv.w;
#pragma unroll
    for (int off = 32; off; off >>= 1) {
        sl += __shfl_down(sl, off);
        sr += __shfl_down(sr, off);
    }
    if (lane == 0) { al[node] = sl; ar[node] = sr; }
}

// ---------------- per-slot coefficient, CSR order (coalesced) ----------------
__global__ void coefcsr_kernel(const int* __restrict__ csr_src, const int* __restrict__ csr_dst,
                               const int* __restrict__ csr_eid, const float* __restrict__ eattr,
                               const float* __restrict__ top, const float* __restrict__ al,
                               const float* __restrict__ ar, float* __restrict__ csr_coef) {
    int k = blockIdx.x * 256 + threadIdx.x;
    int s = csr_src[k], d = csr_dst[k];
    float w = eattr[csr_eid[k]] * top[s] * top[d];
    csr_coef[k] = (w == 0.f) ? 0.f : tanhf(al[s] + ar[d]) * w;
}

// ---------------- gather: h_out[d] = (sum coef*h_in[src] + eps*h0[d]) * top[d]; nrm ----------------
__global__ __launch_bounds__(256) void gather_kernel(
        const int* __restrict__ csr_src, const int* __restrict__ off,
        const float* __restrict__ csr_coef, const float* __restrict__ h_in,
        const float* __restrict__ h0, const float* __restrict__ top,
        float* __restrict__ h_out, float* __restrict__ nrm) {
    int node = blockIdx.x * 4 + (threadIdx.x >> 6);
    int lane = threadIdx.x & 63;
    size_t base = (size_t)node * NHID + lane * 4;
    float t = top[node];
    if (t == 0.f) {
        *(float4*)&h_out[base] = make_float4(0.f, 0.f, 0.f, 0.f);
        if (lane == 0) nrm[node] = 0.f;
        return;
    }
    int k0 = off[node], k1 = off[node + 1];
    float4 acc = make_float4(0.f, 0.f, 0.f, 0.f);
    int k = k0;
    // 4-wide unrolled fast path: 4 independent h-row loads in flight.
    // All per-edge scalars are wave-uniform -> scalar branches.
    for (; k + 3 < k1; k += 4) {
        float c0 = csr_coef[k],     c1 = csr_coef[k + 1];
        float c2 = csr_coef[k + 2], c3 = csr_coef[k + 3];
        int   s0 = csr_src[k],      s1 = csr_src[k + 1];
        int   s2 = csr_src[k + 2],  s3 = csr_src[k + 3];
        if (c0 != 0.f && c1 != 0.f && c2 != 0.f && c3 != 0.f) {
            float4 v0 = *(const float4*)&h_in[(size_t)s0 * NHID + lane * 4];
            float4 v1 = *(const float4*)&h_in[(size_t)s1 * NHID + lane * 4];
            float4 v2 = *(const float4*)&h_in[(size_t)s2 * NHID + lane * 4];
            float4 v3 = *(const float4*)&h_in[(size_t)s3 * NHID + lane * 4];
            acc.x += c0 * v0.x + c1 * v1.x + c2 * v2.x + c3 * v3.x;
            acc.y += c0 * v0.y + c1 * v1.y + c2 * v2.y + c3 * v3.y;
            acc.z += c0 * v0.z + c1 * v1.z + c2 * v2.z + c3 * v3.z;
            acc.w += c0 * v0.w + c1 * v1.w + c2 * v2.w + c3 * v3.w;
        } else {
            if (c0 != 0.f) { float4 v = *(const float4*)&h_in[(size_t)s0 * NHID + lane * 4];
                acc.x += c0 * v.x; acc.y += c0 * v.y; acc.z += c0 * v.z; acc.w += c0 * v.w; }
            if (c1 != 0.f) { float4 v = *(const float4*)&h_in[(size_t)s1 * NHID + lane * 4];
                acc.x += c1 * v.x; acc.y += c1 * v.y; acc.z += c1 * v.z; acc.w += c1 * v.w; }
            if (c2 != 0.f) { float4 v = *(const float4*)&h_in[(size_t)s2 * NHID + lane * 4];
                acc.x += c2 * v.x; acc.y += c2 * v.y; acc.z += c2 * v.z; acc.w += c2 * v.w; }
            if (c3 != 0.f) { float4 v = *(const float4*)&h_in[(size_t)s3 * NHID + lane * 4];
                acc.x += c3 * v.x; acc.y += c3 * v.y; acc.z += c3 * v.z; acc.w += c3 * v.w; }
        }
    }
    for (; k < k1; ++k) {
        float c = csr_coef[k];
        if (c != 0.f) {
            int s = csr_src[k];
            float4 v = *(const float4*)&h_in[(size_t)s * NHID + lane * 4];
            acc.x += c * v.x; acc.y += c * v.y; acc.z += c * v.z; acc.w += c * v.w;
        }
    }
    float4 z = *(const float4*)&h0[base];
    float4 v;
    v.x = acc.x + EPSV * z.x;
    v.y = acc.y + EPSV * z.y;
    v.z = acc.z + EPSV * z.z;
    v.w = acc.w + EPSV * z.w;
    *(float4*)&h_out[base] = v;
    float ss = v.x * v.x + v.y * v.y + v.z * v.z + v.w * v.w;
#pragma unroll
    for (int o = 32; o; o >>= 1) ss += __shfl_down(ss, o);
    if (lane == 0) nrm[node] = sqrtf(ss);
}

// ---------------- per-column stable top-k ----------------
__global__ __launch_bounds__(1024) void topk_kernel(
        const float* __restrict__ nrm, float* __restrict__ top, int drop_from) {
    __shared__ float s[VLEN];
    int c = blockIdx.x;
    int r = threadIdx.x;
    float v = nrm[r * WLEN + c];
    s[r] = v;
    __syncthreads();
    int cnt = 0;
    for (int r2 = 0; r2 < VLEN; ++r2) {
        float v2 = s[r2];
        cnt += (v2 > v) || (v2 == v && r2 < r);
    }
    if (cnt >= drop_from) top[r * WLEN + c] = 0.f;
}

// ---------------- out = (h @ We^T + be) * top via split-bf16 MFMA ----------------
// BM=64 rows/block (4 waves x 16 rows), N=40 padded to 48, K=256.
#define OBSTR 264
__global__ __launch_bounds__(256) void out_mfma(
        const float* __restrict__ h, const float* __restrict__ We,
        const float* __restrict__ be, const float* __restrict__ top,
        float* __restrict__ out) {
    __shared__ unsigned short Bh[48 * OBSTR];
    __shared__ unsigned short Bl[48 * OBSTR];
    __shared__ unsigned short Ah[64 * ASTR];
    __shared__ unsigned short Al[64 * ASTR];
    int tid  = threadIdx.x;
    int w    = tid >> 6;
    int lane = tid & 63;
    int m16  = lane & 15;
    int kblk = lane >> 4;
    int row0 = blockIdx.x * 64;

    // stage We once: 48 rows (40 real + 8 zero) x 256 k, fp32 -> bf16 hi/lo
    for (int i = tid; i < 48 * 64; i += 256) {
        int r = i >> 6, k4 = i & 63;
        float4 v = (r < NCLASS) ? *(const float4*)&We[r * NHID + k4 * 4]
                                : make_float4(0.f, 0.f, 0.f, 0.f);
        ushort4 hh, ll;
        hh.x = f2bf(v.x); ll.x = f2bf(v.x - bf2f(hh.x));
        hh.y = f2bf(v.y); ll.y = f2bf(v.y - bf2f(hh.y));
        hh.z = f2bf(v.z); ll.z = f2bf(v.z - bf2f(hh.z));
        hh.w = f2bf(v.w); ll.w = f2bf(v.w - bf2f(hh.w));
        *(ushort4*)&Bh[r * OBSTR + k4 * 4] = hh;
        *(ushort4*)&Bl[r * OBSTR + k4 * 4] = ll;
    }

    f32x4 acc[3];
#pragma unroll
    for (int nr = 0; nr < 3; ++nr)
#pragma unroll
        for (int e = 0; e < 4; ++e) acc[nr][e] = 0.f;

    for (int kt = 0; kt < NHID; kt += 32) {
#pragma unroll
        for (int i = 0; i < 2; ++i) {
            int f = tid + 256 * i;
            int row = f >> 3, k4 = f & 7;
            float4 v = *(const float4*)&h[(size_t)(row0 + row) * NHID + kt + k4 * 4];
            ushort4 hh, ll;
            hh.x = f2bf(v.x); ll.x = f2bf(v.x - bf2f(hh.x));
            hh.y = f2bf(v.y); ll.y = f2bf(v.y - bf2f(hh.y));
            hh.z = f2bf(v.z); ll.z = f2bf(v.z - bf2f(hh.z));
            hh.w = f2bf(v.w); ll.w = f2bf(v.w - bf2f(hh.w));
            *(ushort4*)&Ah[row * ASTR + k4 * 4] = hh;
            *(ushort4*)&Al[row * ASTR + k4 * 4] = ll;
        }
        __syncthreads();
        int ar_ = w * 16 + m16;
        bf16x8 ah  = *(const bf16x8*)&Ah[ar_ * ASTR + kblk * 8];
        bf16x8 alo = *(const bf16x8*)&Al[ar_ * ASTR + kblk * 8];
#pragma unroll
        for (int nr = 0; nr < 3; ++nr) {
            int br = nr * 16 + m16;
            bf16x8 bh = *(const bf16x8*)&Bh[br * OBSTR + kt + kblk * 8];
            bf16x8 bl = *(const bf16x8*)&Bl[br * OBSTR + kt + kblk * 8];
            acc[nr] = __builtin_amdgcn_mfma_f32_16x16x32_bf16(ah,  bh, acc[nr], 0, 0, 0);
            acc[nr] = __builtin_amdgcn_mfma_f32_16x16x32_bf16(ah,  bl, acc[nr], 0, 0, 0);
            acc[nr] = __builtin_amdgcn_mfma_f32_16x16x32_bf16(alo, bh, acc[nr], 0, 0, 0);
        }
        __syncthreads();
    }
#pragma unroll
    for (int nr = 0; nr < 3; ++nr) {
        int col = nr * 16 + m16;
        if (col < NCLASS) {
            float bias = be[col];
#pragma unroll
            for (int r = 0; r < 4; ++r) {
                int row = row0 + w * 16 + kblk * 4 + r;
                out[(size_t)row * NCLASS + col] = (acc[nr][r] + bias) * top[row];
            }
        }
    }
}

extern "C" void kernel_launch(void* const* d_in, const int* in_sizes, int n_in,
                              void* d_out, int out_size, void* d_ws, size_t ws_size,
                              hipStream_t stream) {
    const float* x     = (const float*)d_in[0];
    const int*   ei    = (const int*)d_in[1];
    const float* eattr = (const float*)d_in[2];
    const float* Ws    = (const float*)d_in[3];
    const float* bs    = (const float*)d_in[4];
    const float* attl  = (const float*)d_in[5];
    const float* attr_ = (const float*)d_in[6];
    const float* We    = (const float*)d_in[7];
    const float* be    = (const float*)d_in[8];
    float* out = (float*)d_out;

    char* ws = (char*)d_ws;
    const size_t HB = (size_t)N_NODES * NHID * sizeof(float);   // 32 MB
    float* hA  = (float*)(ws);
    float* hB  = (float*)(ws + HB);
    float* h0  = (float*)(ws + 2 * HB);
    char* sm = ws + 3 * HB;
    float* al       = (float*)(sm);               sm += 131072;
    float* ar       = (float*)(sm);               sm += 131072;
    float* nrm      = (float*)(sm);               sm += 131072;
    float* top      = (float*)(sm);               sm += 131072;
    int*   cnt      = (int*)(sm);                 sm += 131072;
    int*   cur      = (int*)(sm);                 sm += 131072;
    int*   off      = (int*)(sm);                 sm += 262144;  // 32769 ints
    int*   csr_src  = (int*)(sm);                 sm += E_EDGES * 4;
    int*   csr_dst  = (int*)(sm);                 sm += E_EDGES * 4;
    int*   csr_eid  = (int*)(sm);                 sm += E_EDGES * 4;
    float* csr_coef = (float*)(sm);               sm += E_EDGES * 4;
    unsigned short* Whi = (unsigned short*)(sm);  sm += NHID * NFEAT * 2;
    unsigned short* Wlo = (unsigned short*)(sm);  sm += NHID * NFEAT * 2;

    const int* srcp = ei;
    const int* dstp = ei + E_EDGES;

    init_kernel<<<N_NODES / 256, 256, 0, stream>>>(top, cnt, cur);
    count_kernel<<<E_EDGES / 256, 256, 0, stream>>>(dstp, cnt);
    scan_kernel<<<1, 1024, 0, stream>>>(cnt, off);
    scatter_kernel<<<E_EDGES / 256, 256, 0, stream>>>(srcp, dstp, off, cur,
                                                      csr_src, csr_dst, csr_eid);

    wsplit_kernel<<<(NHID * NFEAT / 4) / 256, 256, 0, stream>>>(Ws, Whi, Wlo);
    gemm_mfma<<<N_NODES / 64, 256, 0, stream>>>(x, Whi, Wlo, bs, h0);

    float* hin = h0;
    float* hout = hA;
    for (int l = 0; l < 2; ++l) {
        dots_kernel<<<N_NODES / 4, 256, 0, stream>>>(hin, attl + l * NHID, attr_ + l * NHID, al, ar);
        coefcsr_kernel<<<E_EDGES / 256, 256, 0, stream>>>(csr_src, csr_dst, csr_eid, eattr,
                                                          top, al, ar, csr_coef);
        gather_kernel<<<N_NODES / 4, 256, 0, stream>>>(csr_src, off, csr_coef,
                                                       hin, h0, top, hout, nrm);
        int drop_from = (l == 0) ? 256 : 128;
        topk_kernel<<<WLEN, VLEN, 0, stream>>>(nrm, top, drop_from);
        hin = hout;
        hout = (hout == hA) ? hB : hA;
    }

    out_mfma<<<N_NODES / 64, 256, 0, stream>>>(hin, We, be, top, out);
}